// Round 7
// baseline (1686.927 us; speedup 1.0000x reference)
//
#include <hip/hip_runtime.h>

// VGG16-A spiking NN, multi-compartment LIF (K=2), T=3, B=4, fp32.
// Round 7: PERSISTENT MEGAKERNEL. 48 dispatches -> 1. 256 blocks x 512
// threads (<=1 block/CU -> co-resident by construction); monotonic atomic
// grid barrier between stages (45 barriers). Stage bodies are the proven
// round-6 kernels as block-stride device functions.

#define BATCH 4
#define NBLK 256
#define NTHR 512

__device__ __forceinline__ float lif_update(float mem_in, float syn, float thr,
                                            float leak, float* mem_out) {
    float m = leak * mem_in + syn;
    float val = 0.f;
    if ((m / thr - 1.f > 0.f) && (1.f - m / (2.f * thr) >= 0.f)) val += 1.f;
    if ((m / (2.f * thr) - 1.f > 0.f) && (1.f - m / (4.f * thr) >= 0.f)) val += 2.f;
    *mem_out = m - thr * val;
    return val;
}

// Grid barrier: monotonic counter, release/acquire fences, tid0 spins.
// All 256 blocks are co-resident (grid == 256 <= #CUs), so no deadlock.
__device__ __forceinline__ void gbar(unsigned* cnt, unsigned* target) {
    __syncthreads();
    if (threadIdx.x == 0) {
        __threadfence();              // release: publish this block's stores
        atomicAdd(cnt, 1u);
        *target += NBLK;
        while (__hip_atomic_load(cnt, __ATOMIC_RELAXED,
                                 __HIP_MEMORY_SCOPE_AGENT) < *target)
            __builtin_amdgcn_s_sleep(1);
        __threadfence();              // acquire: invalidate stale caches
    }
    __syncthreads();
}

// Layer 0: element-per-thread conv+LIF (IC=3), block-stride.
__device__ void conv0_stage(const float* __restrict__ in,
                            const float* __restrict__ w,
                            float* __restrict__ mem, float* __restrict__ out,
                            float thr, float leak, int first) {
    const int IC = 3, OC = 64, H = 32, W = 32;
    int n = BATCH * OC * H * W;
    for (int idx = blockIdx.x * NTHR + threadIdx.x; idx < n; idx += NBLK * NTHR) {
        int x = idx % W;
        int y = (idx / W) % H;
        int oc = (idx / (W * H)) % OC;
        int b = idx / (W * H * OC);
        const float* wp = w + (size_t)oc * IC * 9;
        const float* ip = in + (size_t)b * IC * H * W;
        float syn = 0.f;
        for (int ic = 0; ic < IC; ++ic) {
            const float* ipc = ip + (size_t)ic * H * W;
            const float* wpc = wp + ic * 9;
#pragma unroll
            for (int ky = 0; ky < 3; ++ky) {
                int yy = y + ky - 1;
                if (yy < 0 || yy >= H) continue;
#pragma unroll
                for (int kx = 0; kx < 3; ++kx) {
                    int xx = x + kx - 1;
                    if (xx < 0 || xx >= W) continue;
                    syn = fmaf(ipc[yy * W + xx], wpc[ky * 3 + kx], syn);
                }
            }
        }
        float mi = first ? 0.f : mem[idx];
        float mo;
        float val = lif_update(mi, syn, thr, leak, &mo);
        mem[idx] = mo;
        out[idx] = val;
    }
}

// Layers 1-6: lane=pixel, 8 waves split IC, LDS reduce, optional fused pool.
// Software-pipelined ic loop. Block-stride over NB = B*chunks*ocg.
template <int OCT, int POOL>
__device__ void conv_mid_stage(const float* __restrict__ in,
                               const float* __restrict__ w,
                               float* __restrict__ mem,
                               float* __restrict__ out,
                               float thr, float leak,
                               int IC, int OC, int H, int W, int first,
                               float* smem) {
    constexpr int NW = 8;
    const int tid = threadIdx.x;
    const int lane = tid & 63;
    const int wv = tid >> 6;
    const int ocg = OC / OCT;
    const int HW = H * W;
    const int chunks = HW >> 6;
    const int NB = BATCH * chunks * ocg;
    const int rpw = 64 / W;
    float* red = smem;                   // [NW][OCT][64]
    float* vals = smem + NW * OCT * 64;  // [OCT][64]

    for (int bid = blockIdx.x; bid < NB; bid += NBLK) {
        __syncthreads();  // protect LDS reuse across iterations/stages
        int g = bid % ocg;
        int ch = (bid / ocg) % chunks;
        int b = bid / (ocg * chunks);
        int y = ch * rpw + lane / W;
        int x = lane % W;
        int oc0 = g * OCT;

        int off[9];
        bool msk[9];
#pragma unroll
        for (int ky = 0; ky < 3; ++ky)
#pragma unroll
            for (int kx = 0; kx < 3; ++kx) {
                int yy = y + ky - 1, xx = x + kx - 1;
                bool vv = (yy >= 0 && yy < H && xx >= 0 && xx < W);
                msk[ky * 3 + kx] = vv;
                off[ky * 3 + kx] = vv ? yy * W + xx : 0;
            }

        float acc[OCT];
#pragma unroll
        for (int t = 0; t < OCT; ++t) acc[t] = 0.f;

        const float* ibase = in + (size_t)b * IC * HW;
        const float* wbase = w + (size_t)oc0 * IC * 9;
        int icpw = IC / NW;
        int ic0 = wv * icpw;
        int icend = ic0 + icpw;

        float v[9];
        {
            const float* ip = ibase + (size_t)ic0 * HW;
#pragma unroll
            for (int k = 0; k < 9; ++k) v[k] = msk[k] ? ip[off[k]] : 0.f;
        }
        for (int ic = ic0; ic < icend; ++ic) {
            int icn = (ic + 1 < icend) ? ic + 1 : ic;
            const float* ipn = ibase + (size_t)icn * HW;
            float nv[9];
#pragma unroll
            for (int k = 0; k < 9; ++k) nv[k] = msk[k] ? ipn[off[k]] : 0.f;
            const float* wp = wbase + (size_t)ic * 9;
#pragma unroll
            for (int t = 0; t < OCT; ++t) {
                const float* wt = wp + (size_t)t * IC * 9;
#pragma unroll
                for (int k = 0; k < 9; ++k) acc[t] = fmaf(v[k], wt[k], acc[t]);
            }
#pragma unroll
            for (int k = 0; k < 9; ++k) v[k] = nv[k];
        }

#pragma unroll
        for (int t = 0; t < OCT; ++t) red[(wv * OCT + t) * 64 + lane] = acc[t];
        __syncthreads();

        for (int s = tid; s < OCT * 64; s += NW * 64) {
            int t = s >> 6, p = s & 63;
            float sum = 0.f;
#pragma unroll
            for (int q = 0; q < NW; ++q) sum += red[(q * OCT + t) * 64 + p];
            size_t idx = (size_t)(b * OC + oc0 + t) * HW + ch * 64 + p;
            float mi = first ? 0.f : mem[idx];
            float mo;
            float val = lif_update(mi, sum, thr, leak, &mo);
            mem[idx] = mo;
            if (POOL) vals[t * 64 + p] = val;
            else out[idx] = val;
        }
        if (POOL) {
            __syncthreads();
            int Wo = W >> 1, Ho = H >> 1;
            for (int s = tid; s < OCT * 16; s += NW * 64) {
                int t = s >> 4, q = s & 15;
                int pr = q / Wo, pc = q % Wo;
                float pv = 0.25f * (vals[t * 64 + (2 * pr) * W + 2 * pc] +
                                    vals[t * 64 + (2 * pr) * W + 2 * pc + 1] +
                                    vals[t * 64 + (2 * pr + 1) * W + 2 * pc] +
                                    vals[t * 64 + (2 * pr + 1) * W + 2 * pc + 1]);
                size_t pidx = ((size_t)(b * OC + oc0 + t) * Ho +
                               (ch * (rpw >> 1) + pr)) * Wo + pc;
                out[pidx] = pv;
            }
        }
    }
}

// Layers 7-12: one oc per bid; 8 waves split IC (ic = lane + 64*wv); plane
// in registers; per-wave butterfly transpose-reduce; LDS cross-wave reduce.
template <int S, int POOL>
__device__ void conv_small_stage(const float* __restrict__ in,
                                 const float* __restrict__ w,
                                 float* __restrict__ mem,
                                 float* __restrict__ out,
                                 float thr, float leak,
                                 int IC, int OC, int first, float* smem) {
    constexpr int SS = S * S;
    constexpr int M = 4 * SS;
    constexpr int LOG2M = (S == 4) ? 6 : 4;
    const int tid = threadIdx.x;
    const int lane = tid & 63;
    const int wv = tid >> 6;
    float* red = smem;        // [8][M]
    float* pvs = smem + 8 * M;  // [M]

    for (int oc = blockIdx.x; oc < OC; oc += NBLK) {
        __syncthreads();
        float acc[M];
#pragma unroll
        for (int i = 0; i < M; ++i) acc[i] = 0.f;

        const float* wrow = w + (size_t)oc * IC * 9;
        for (int ic = lane + (wv << 6); ic < IC; ic += NTHR) {
            const float* wp = wrow + (size_t)ic * 9;
            float wvv[9];
#pragma unroll
            for (int k = 0; k < 9; ++k) wvv[k] = wp[k];
#pragma unroll
            for (int b = 0; b < 4; ++b) {
                const float4* ip = (const float4*)(in + (size_t)(b * IC + ic) * SS);
                float pv[SS];
#pragma unroll
                for (int q = 0; q < SS / 4; ++q) {
                    float4 t4 = ip[q];
                    pv[4 * q + 0] = t4.x;
                    pv[4 * q + 1] = t4.y;
                    pv[4 * q + 2] = t4.z;
                    pv[4 * q + 3] = t4.w;
                }
#pragma unroll
                for (int y = 0; y < S; ++y)
#pragma unroll
                    for (int x = 0; x < S; ++x) {
                        float a = acc[b * SS + y * S + x];
#pragma unroll
                        for (int ky = 0; ky < 3; ++ky) {
                            int yy = y + ky - 1;
                            if (yy < 0 || yy >= S) continue;
#pragma unroll
                            for (int kx = 0; kx < 3; ++kx) {
                                int xx = x + kx - 1;
                                if (xx < 0 || xx >= S) continue;
                                a = fmaf(pv[yy * S + xx], wvv[ky * 3 + kx], a);
                            }
                        }
                        acc[b * SS + y * S + x] = a;
                    }
            }
        }

#pragma unroll
        for (int step = 0; step < LOG2M; ++step) {
            const int offx = 1 << step;
            const int half = M >> (step + 1);
            const bool hi = (lane & offx) != 0;
#pragma unroll
            for (int i = 0; i < half; ++i) {
                float sent = hi ? acc[i] : acc[i + half];
                float got = __shfl_xor(sent, offx);
                acc[i] = (hi ? acc[i + half] : acc[i]) + got;
            }
        }
        float sum = acc[0];
#pragma unroll
        for (int offx = M; offx < 64; offx <<= 1) sum += __shfl_xor(sum, offx);

        int o = (int)(__brev((unsigned)(lane & (M - 1))) >> (32 - LOG2M));
        if (lane < M) red[wv * M + o] = sum;
        __syncthreads();

        if (tid < M) {
            float tot = 0.f;
#pragma unroll
            for (int q = 0; q < 8; ++q) tot += red[q * M + tid];
            int b = tid / SS, p = tid % SS;
            size_t idx = (size_t)(b * OC + oc) * SS + p;
            float mi = first ? 0.f : mem[idx];
            float mo;
            float val = lif_update(mi, tot, thr, leak, &mo);
            mem[idx] = mo;
            if (POOL) pvs[tid] = val;
            else out[idx] = val;
        }
        if (POOL) {
            __syncthreads();
            constexpr int Sh = S / 2, SSh = Sh * Sh;
            if (tid < 4 * SSh) {
                int b = tid / SSh, q = tid % SSh;
                int pr = q / Sh, pc = q % Sh;
                float pv = 0.25f * (pvs[b * SS + (2 * pr) * S + 2 * pc] +
                                    pvs[b * SS + (2 * pr) * S + 2 * pc + 1] +
                                    pvs[b * SS + (2 * pr + 1) * S + 2 * pc] +
                                    pvs[b * SS + (2 * pr + 1) * S + 2 * pc + 1]);
                out[((size_t)(b * OC + oc) * Sh + pr) * Sh + pc] = pv;
            }
        }
    }
}

// FC+LIF: wave-per-output-neuron, wave-stride loop.
__device__ void fc_stage(const float* __restrict__ in, const float* __restrict__ w,
                         float* __restrict__ mem, float* __restrict__ out,
                         float thr, float leak, int Kd, int N, int first) {
    int gw = blockIdx.x * (NTHR / 64) + (threadIdx.x >> 6);
    int lane = threadIdx.x & 63;
    int GW = NBLK * (NTHR / 64);
    int K4 = Kd >> 2;
    const float4* ip = (const float4*)in;
    for (int j = gw; j < N; j += GW) {
        const float4* wp = (const float4*)(w + (size_t)j * Kd);
        float a0 = 0.f, a1 = 0.f, a2 = 0.f, a3 = 0.f;
        for (int k = lane; k < K4; k += 64) {
            float4 wv = wp[k];
            float4 v0 = ip[k];
            float4 v1 = ip[K4 + k];
            float4 v2 = ip[2 * K4 + k];
            float4 v3 = ip[3 * K4 + k];
            a0 = fmaf(wv.x, v0.x, fmaf(wv.y, v0.y, fmaf(wv.z, v0.z, fmaf(wv.w, v0.w, a0))));
            a1 = fmaf(wv.x, v1.x, fmaf(wv.y, v1.y, fmaf(wv.z, v1.z, fmaf(wv.w, v1.w, a1))));
            a2 = fmaf(wv.x, v2.x, fmaf(wv.y, v2.y, fmaf(wv.z, v2.z, fmaf(wv.w, v2.w, a2))));
            a3 = fmaf(wv.x, v3.x, fmaf(wv.y, v3.y, fmaf(wv.z, v3.z, fmaf(wv.w, v3.w, a3))));
        }
#pragma unroll
        for (int off = 32; off > 0; off >>= 1) {
            a0 += __shfl_xor(a0, off);
            a1 += __shfl_xor(a1, off);
            a2 += __shfl_xor(a2, off);
            a3 += __shfl_xor(a3, off);
        }
        if (lane == 0) {
            float accv[4] = {a0, a1, a2, a3};
#pragma unroll
            for (int b = 0; b < BATCH; ++b) {
                float mi = first ? 0.f : mem[(size_t)b * N + j];
                float mo;
                float val = lif_update(mi, accv[b], thr, leak, &mo);
                mem[(size_t)b * N + j] = mo;
                out[(size_t)b * N + j] = val;
            }
        }
    }
}

// Final linear: 40 wave-tasks; logits overwritten at t==0, accumulated after.
__device__ void fc2_stage(const float* __restrict__ in, const float* __restrict__ w,
                          float* __restrict__ logits, int Kd, int L, int init) {
    int gw = blockIdx.x * (NTHR / 64) + (threadIdx.x >> 6);
    int lane = threadIdx.x & 63;
    if (gw >= BATCH * L) return;
    int l = gw % L;
    int b = gw / L;
    int K4 = Kd >> 2;
    const float4* ip = (const float4*)(in + (size_t)b * Kd);
    const float4* wp = (const float4*)(w + (size_t)l * Kd);
    float s = 0.f;
    for (int k = lane; k < K4; k += 64) {
        float4 iv = ip[k];
        float4 wv = wp[k];
        s = fmaf(iv.x, wv.x, fmaf(iv.y, wv.y, fmaf(iv.z, wv.z, fmaf(iv.w, wv.w, s))));
    }
#pragma unroll
    for (int off = 32; off > 0; off >>= 1) s += __shfl_xor(s, off);
    if (lane == 0) logits[gw] = init ? s : logits[gw] + s;
}

struct MegaArgs {
    const float* x;
    const float* cw[13];
    const float* fc0;
    const float* fc1;
    const float* fc2;
    const float* thr;
    const float* leak;
    float* cm[13];
    float* mfc0;
    float* mfc1;
    float* buf0;
    float* buf1;
    float* buf2;
    float* logits;
    unsigned* bar;
};

__global__ __launch_bounds__(NTHR) void vgg_mega(MegaArgs a) {
    __shared__ float smem[8 * 8 * 64 + 8 * 64];  // 20 KB arena (max stage need)
    unsigned target = 0;
    for (int t = 0; t < 3; ++t) {
        int first = (t == 0);
        conv0_stage(a.x, a.cw[0], a.cm[0], a.buf0, a.thr[0], a.leak[0], first);
        gbar(a.bar, &target);
        conv_mid_stage<8, 1>(a.buf0, a.cw[1], a.cm[1], a.buf1, a.thr[1], a.leak[1],
                             64, 64, 32, 32, first, smem);
        gbar(a.bar, &target);
        conv_mid_stage<4, 0>(a.buf1, a.cw[2], a.cm[2], a.buf2, a.thr[2], a.leak[2],
                             64, 128, 16, 16, first, smem);
        gbar(a.bar, &target);
        conv_mid_stage<4, 1>(a.buf2, a.cw[3], a.cm[3], a.buf0, a.thr[3], a.leak[3],
                             128, 128, 16, 16, first, smem);
        gbar(a.bar, &target);
        conv_mid_stage<4, 0>(a.buf0, a.cw[4], a.cm[4], a.buf1, a.thr[4], a.leak[4],
                             128, 256, 8, 8, first, smem);
        gbar(a.bar, &target);
        conv_mid_stage<4, 0>(a.buf1, a.cw[5], a.cm[5], a.buf2, a.thr[5], a.leak[5],
                             256, 256, 8, 8, first, smem);
        gbar(a.bar, &target);
        conv_mid_stage<4, 1>(a.buf2, a.cw[6], a.cm[6], a.buf0, a.thr[6], a.leak[6],
                             256, 256, 8, 8, first, smem);
        gbar(a.bar, &target);
        conv_small_stage<4, 0>(a.buf0, a.cw[7], a.cm[7], a.buf1, a.thr[7], a.leak[7],
                               256, 512, first, smem);
        gbar(a.bar, &target);
        conv_small_stage<4, 0>(a.buf1, a.cw[8], a.cm[8], a.buf2, a.thr[8], a.leak[8],
                               512, 512, first, smem);
        gbar(a.bar, &target);
        conv_small_stage<4, 1>(a.buf2, a.cw[9], a.cm[9], a.buf0, a.thr[9], a.leak[9],
                               512, 512, first, smem);
        gbar(a.bar, &target);
        conv_small_stage<2, 0>(a.buf0, a.cw[10], a.cm[10], a.buf1, a.thr[10],
                               a.leak[10], 512, 512, first, smem);
        gbar(a.bar, &target);
        conv_small_stage<2, 0>(a.buf1, a.cw[11], a.cm[11], a.buf2, a.thr[11],
                               a.leak[11], 512, 512, first, smem);
        gbar(a.bar, &target);
        conv_small_stage<2, 0>(a.buf2, a.cw[12], a.cm[12], a.buf0, a.thr[12],
                               a.leak[12], 512, 512, first, smem);
        gbar(a.bar, &target);
        fc_stage(a.buf0, a.fc0, a.mfc0, a.buf1, a.thr[13], a.leak[13],
                 2048, 4096, first);
        gbar(a.bar, &target);
        fc_stage(a.buf1, a.fc1, a.mfc1, a.buf2, a.thr[14], a.leak[14],
                 4096, 4096, first);
        gbar(a.bar, &target);
        fc2_stage(a.buf2, a.fc2, a.logits, 4096, 10, first);
        // no barrier needed after fc2: next stages touching buf2 are >=2
        // barriers away; buf0 was last read by fc0 (already barriered).
    }
}

extern "C" void kernel_launch(void* const* d_in, const int* in_sizes, int n_in,
                              void* d_out, int out_size, void* d_ws, size_t ws_size,
                              hipStream_t stream) {
    MegaArgs a;
    a.x = (const float*)d_in[0];
    for (int i = 0; i < 13; ++i) a.cw[i] = (const float*)d_in[1 + i];
    a.fc0 = (const float*)d_in[14];
    a.fc1 = (const float*)d_in[15];
    a.fc2 = (const float*)d_in[16];
    a.thr = (const float*)d_in[17];
    a.leak = (const float*)d_in[18];

    static const int OC[13] = {64, 64, 128, 128, 256, 256, 256, 512, 512, 512, 512, 512, 512};
    static const int HH[13] = {32, 32, 16, 16, 8, 8, 8, 4, 4, 4, 2, 2, 2};

    float* ws = (float*)d_ws;
    size_t off = 0;
    for (int i = 0; i < 13; ++i) {
        a.cm[i] = ws + off;
        off += (size_t)BATCH * OC[i] * HH[i] * HH[i];
    }
    a.mfc0 = ws + off; off += BATCH * 4096;
    a.mfc1 = ws + off; off += BATCH * 4096;
    a.buf0 = ws + off; off += 262144;
    a.buf1 = ws + off; off += 262144;
    a.buf2 = ws + off; off += 262144;
    a.bar = (unsigned*)(ws + off); off += 16;
    a.logits = (float*)d_out;

    hipMemsetAsync((void*)a.bar, 0, sizeof(unsigned), stream);
    vgg_mega<<<NBLK, NTHR, 0, stream>>>(a);
}